// Round 10
// baseline (1118.816 us; speedup 1.0000x reference)
//
#include <hip/hip_runtime.h>

// ---------------------------------------------------------------------------
// BiLSTM-CRF forward loss on MI355X (gfx950).
// memset(out=NaN)x2 + prep -> LSTM layer0 (fused input-proj)
//   -> LSTM layer1 (fused input-proj) -> heads GEMM -> CRF.
// Round 10: identical to R9 except lstm_rec is launched with plain
// hipLaunchKernelGGL. The sentinel-dataflow design needs only co-residency
// (128 blocks, 1/CU on a 256-CU chip) — not grid.sync — and the cooperative
// launcher's occupancy validation (which can silently reject this
// high-VGPR/53.5KB-LDS kernel, leaving out* = NaN) is the prime suspect for
// R8/R9's NaN.
// ---------------------------------------------------------------------------

typedef unsigned short u16;
typedef unsigned int u32;
typedef unsigned long long u64;
typedef __attribute__((ext_vector_type(8))) __bf16 bf16x8;
typedef __attribute__((ext_vector_type(4))) float floatx4;

static __device__ __forceinline__ u16 f2bf(float f) {
  u32 u = __float_as_uint(f);
  u += 0x7fffu + ((u >> 16) & 1u);   // round-to-nearest-even
  return (u16)(u >> 16);
}
static __device__ __forceinline__ float sigf(float x) {
  return 1.0f / (1.0f + __expf(-x));
}
static __device__ __forceinline__ float tanh_(float x) {
  return 1.0f - 2.0f / (1.0f + __expf(2.0f * x));
}
static __device__ __forceinline__ floatx4 mfma16(bf16x8 a, bf16x8 b, floatx4 c) {
  return __builtin_amdgcn_mfma_f32_16x16x32_bf16(a, b, c, 0, 0, 0);
}

// ---------------------------------------------------------------------------
// prep: fp32->bf16 conversions, emb assembly ([src|bert] bcast), bias sums
// ---------------------------------------------------------------------------
__global__ __launch_bounds__(256) void prep_kernel(
    const float* __restrict__ w_ih, const float* __restrict__ w_hh,
    const float* __restrict__ b_ih, const float* __restrict__ b_hh,
    const float* __restrict__ src,  const float* __restrict__ bert,
    const float* __restrict__ hwp,  const float* __restrict__ hwm,
    const float* __restrict__ hbp,  const float* __restrict__ hbm,
    u16* __restrict__ Wih, u16* __restrict__ Whh, u16* __restrict__ emb,
    u16* __restrict__ Wheads, float* __restrict__ bsum, float* __restrict__ hb,
    float* __restrict__ dout)
{
  const int NA = 8388608;  // w_ih both layers -> Wih bf16
  const int NB = 4194304;  // w_hh both layers -> Whh bf16
  const int NC = 1048576;  // src -> emb[.., 0:256]
  const int ND = 3145728;  // bert broadcast -> emb[.., 256:1024]
  const int NE = 98304;    // head weights
  const int NF = 8192;     // bias sums
  const int NG = 96;       // head bias
  const int TOTAL = NA + NB + NC + ND + NE + NF + NG + 1;
  for (int i = blockIdx.x * 256 + threadIdx.x; i < TOTAL; i += gridDim.x * 256) {
    int x = i;
    if (x < NA) { Wih[x] = f2bf(w_ih[x]); continue; }
    x -= NA;
    if (x < NB) { Whh[x] = f2bf(w_hh[x]); continue; }
    x -= NB;
    if (x < NC) {
      const int row = x >> 8, c = x & 255;       // row = s*32+b
      emb[row * 1024 + c] = f2bf(src[x]);
      continue;
    }
    x -= NC;
    if (x < ND) {
      const int sb = x / 768, c = x - sb * 768;  // sb = s*32+b
      emb[sb * 1024 + 256 + c] = f2bf(bert[(sb & 31) * 768 + c]);
      continue;
    }
    x -= ND;
    if (x < NE) { Wheads[x] = f2bf(x < 32768 ? hwp[x] : hwm[x - 32768]); continue; }
    x -= NE;
    if (x < NF) { bsum[x] = b_ih[x] + b_hh[x]; continue; }
    x -= NF;
    if (x < NG) { hb[x] = (x < 32) ? hbp[x] : hbm[x - 32]; continue; }
    dout[0] = 0.f;
  }
}

// ---------------------------------------------------------------------------
// bf16 NT GEMM (heads only): C[m][n] = sum_k A[m][k]*B[n][k] + bias[n]
// 128x128 tile, BK=64, XOR-swizzled LDS.
// ---------------------------------------------------------------------------
__global__ __launch_bounds__(256) void gemm_nt(
    const u16* __restrict__ A, int lda,
    const u16* __restrict__ B, int ldb,
    float* __restrict__ C, int ldc,
    int M, int N, int K,
    const float* __restrict__ bias_n)
{
  __shared__ __align__(16) u16 As[128 * 64];
  __shared__ __align__(16) u16 Bs[128 * 64];
  const int m0 = blockIdx.y * 128, n0 = blockIdx.x * 128;
  const int tid = threadIdx.x;
  const int wv = tid >> 6, ln = tid & 63;
  const int wm = wv & 1, wn = wv >> 1;
  const int q = ln >> 4, l15 = ln & 15;
  floatx4 acc[4][4];
#pragma unroll
  for (int a = 0; a < 4; ++a)
#pragma unroll
    for (int b2 = 0; b2 < 4; ++b2) acc[a][b2] = (floatx4){0.f, 0.f, 0.f, 0.f};

  for (int kk = 0; kk < K; kk += 64) {
    __syncthreads();
#pragma unroll
    for (int j = 0; j < 4; ++j) {
      const int idx = j * 256 + tid;
      const int r = idx >> 3, cc = idx & 7;
      const int slot = cc ^ (r & 7);
      const int ra = min(m0 + r, M - 1);
      *(int4*)&As[r * 64 + slot * 8] = *(const int4*)&A[(long)ra * lda + kk + cc * 8];
      const int rb = min(n0 + r, N - 1);
      *(int4*)&Bs[r * 64 + slot * 8] = *(const int4*)&B[(long)rb * ldb + kk + cc * 8];
    }
    __syncthreads();
#pragma unroll
    for (int ks = 0; ks < 2; ++ks) {
      bf16x8 af[4], bf[4];
#pragma unroll
      for (int im = 0; im < 4; ++im) {
        const int r = wm * 64 + im * 16 + l15;
        const int slot = (ks * 4 + q) ^ (r & 7);
        af[im] = *(const bf16x8*)&As[r * 64 + slot * 8];
      }
#pragma unroll
      for (int jn = 0; jn < 4; ++jn) {
        const int r = wn * 64 + jn * 16 + l15;
        const int slot = (ks * 4 + q) ^ (r & 7);
        bf[jn] = *(const bf16x8*)&Bs[r * 64 + slot * 8];
      }
#pragma unroll
      for (int im = 0; im < 4; ++im)
#pragma unroll
        for (int jn = 0; jn < 4; ++jn)
          acc[im][jn] = mfma16(af[im], bf[jn], acc[im][jn]);
    }
  }
#pragma unroll
  for (int im = 0; im < 4; ++im)
#pragma unroll
    for (int jn = 0; jn < 4; ++jn) {
      const int n = n0 + wn * 64 + jn * 16 + l15;
      if (n < N) {
        const float badd = bias_n ? bias_n[n] : 0.f;
#pragma unroll
        for (int rg = 0; rg < 4; ++rg) {
          const int m = m0 + wm * 64 + im * 16 + q * 4 + rg;
          if (m < M) C[(long)m * ldc + n] = acc[im][jn][rg] + badd;
        }
      }
    }
}

// ---------------------------------------------------------------------------
// persistent LSTM recurrence with FUSED input projection (normal launch;
// 128 blocks x 256 thr co-resident at 1 block/CU on 256 CUs).
// block = (dir, batch-half of 16, 16 hidden units).
// Dataflow sync: out pre-filled with bf16 NaN; producers store h as atomic
// u64; consumers retry coalesced atomic u64 loads until non-sentinel.
// Per step: [x(t+1) glob->regs] [h retry] [x->LDS, h->LDS] [sync]
// [h-MFMA] [x-MFMA -> gin(t+1)] [g=acc+gin(t), act, h store].
// Single x_lds is safe: the h-store data-depends on the gsc LDS reads, whose
// waitcnt drains this wave's x/h ds_reads; other blocks can only overwrite
// x_lds after observing that h store (sentinel retry chain).
// ---------------------------------------------------------------------------
__global__ __launch_bounds__(256, 1) void lstm_rec(
    const u16* __restrict__ xbuf,   // [128][32][1024] bf16 (emb or out0)
    u16* __restrict__ out,          // [128][32][1024] bf16 (NaN-prefilled)
    const u16* __restrict__ wih,    // [2][2048][1024] bf16 (this layer)
    const u16* __restrict__ whh,    // [2][2048][512] bf16 (this layer)
    const float* __restrict__ bsum) // [2][2048] fp32 (this layer)
{
  __shared__ __align__(16) u16 x_lds[16 * 1024];
  __shared__ __align__(16) u16 h_lds[16 * 512];
  __shared__ float gsc[4][16][17];
  const int bid = blockIdx.x;
  const int dir = bid >> 6;
  const int mh = (bid >> 5) & 1;
  const int ub = bid & 31;
  const int u0 = ub * 16;
  const int tid = threadIdx.x;
  const int wv = tid >> 6;
  const int ln = tid & 63;
  const int q = ln >> 4, l15 = ln & 15;

  // gate row for this lane's B-frag column n=l15
  const int gate_r = (l15 >> 2) * 512 + u0 + wv * 4 + (l15 & 3);

  bf16x8 bh[16];
  {
    const u16* wp = whh + ((long)dir * 2048 + gate_r) * 512 + q * 8;
#pragma unroll
    for (int ks = 0; ks < 16; ++ks) bh[ks] = *(const bf16x8*)(wp + ks * 32);
  }
  bf16x8 bx[32];
  {
    const u16* wp = wih + ((long)dir * 2048 + gate_r) * 1024 + q * 8;
#pragma unroll
    for (int ks = 0; ks < 32; ++ks) bx[ks] = *(const bf16x8*)(wp + ks * 32);
  }
  const float bias_r = bsum[dir * 2048 + gate_r];

  float c = 0.f;
  const int b_glob = mh * 16 + l15;

  // ---- prologue: stage x[s0] -> x_lds, gin(0) = bias + Wx x[s0] ----
  floatx4 gin;
  {
    const int s0 = dir ? 127 : 0;
    const u64* xp = (const u64*)(xbuf + ((long)s0 * 32 + mh * 16) * 1024);
#pragma unroll
    for (int j = 0; j < 16; ++j) {
      const int idx = j * 256 + tid;            // 4096 contiguous u64
      const u64 v = xp[idx];
      const int r = idx >> 8, c4 = idx & 255;
      const int cc8 = c4 >> 1, hf = c4 & 1;
      const int slot = (cc8 & ~7) | ((cc8 & 7) ^ (r & 7));
      *(u64*)&x_lds[r * 1024 + slot * 8 + hf * 4] = v;
    }
    __syncthreads();
    floatx4 gx0 = (floatx4){bias_r, bias_r, bias_r, bias_r};
    floatx4 gx1 = (floatx4){0.f, 0.f, 0.f, 0.f};
#pragma unroll
    for (int ks = 0; ks < 32; ks += 2) {
      const int c0 = ks * 4 + q;
      const int slot0 = (c0 & ~7) | ((c0 & 7) ^ (l15 & 7));
      bf16x8 a0 = *(const bf16x8*)&x_lds[l15 * 1024 + slot0 * 8];
      gx0 = mfma16(a0, bx[ks], gx0);
      const int c1 = (ks + 1) * 4 + q;
      const int slot1 = (c1 & ~7) | ((c1 & 7) ^ (l15 & 7));
      bf16x8 a1 = *(const bf16x8*)&x_lds[l15 * 1024 + slot1 * 8];
      gx1 = mfma16(a1, bx[ks + 1], gx1);
    }
    gin = gx0 + gx1;
    __syncthreads();   // protect x_lds until every wave consumed x[s0]
  }

  for (int t = 0; t < 128; ++t) {
    const int s = dir ? (127 - t) : t;
    // 1. x[s(t+1)] global loads into registers (before the h retry so both
    //    drain together in the retry's first waitcnt)
    u64 xv[16];
    if (t < 127) {
      const int sn = dir ? (126 - t) : (t + 1);
      const u64* xp = (const u64*)(xbuf + ((long)sn * 32 + mh * 16) * 1024);
#pragma unroll
      for (int j = 0; j < 16; ++j) xv[j] = xp[j * 256 + tid];
    }
    // 2. h(t-1) staging with sentinel retry
    u64 v8[8];
    if (t > 0) {
      const int sp = dir ? (s + 1) : (s - 1);
      const u64* ubp = (const u64*)(out + (((long)sp * 32 + mh * 16) * 1024 + (long)dir * 512));
#pragma unroll
      for (int j = 0; j < 8; ++j) {
        const int idx = j * 256 + tid;
        const int r = idx >> 7, c4 = idx & 127;
        v8[j] = __hip_atomic_load((u64*)(ubp + (long)r * 256 + c4),
                                  __ATOMIC_RELAXED, __HIP_MEMORY_SCOPE_AGENT);
      }
      while (true) {
        bool bad = false;
#pragma unroll
        for (int j = 0; j < 8; ++j) bad |= ((v8[j] & 0xffffULL) == 0xffffULL);
        if (!bad) break;
#pragma unroll
        for (int j = 0; j < 8; ++j) {
          if ((v8[j] & 0xffffULL) == 0xffffULL) {
            const int idx = j * 256 + tid;
            const int r = idx >> 7, c4 = idx & 127;
            v8[j] = __hip_atomic_load((u64*)(ubp + (long)r * 256 + c4),
                                      __ATOMIC_RELAXED, __HIP_MEMORY_SCOPE_AGENT);
          }
        }
      }
    }
    // 3. LDS writes (x then h)
    if (t < 127) {
#pragma unroll
      for (int j = 0; j < 16; ++j) {
        const int idx = j * 256 + tid;
        const int r = idx >> 8, c4 = idx & 255;
        const int cc8 = c4 >> 1, hf = c4 & 1;
        const int slot = (cc8 & ~7) | ((cc8 & 7) ^ (r & 7));
        *(u64*)&x_lds[r * 1024 + slot * 8 + hf * 4] = xv[j];
      }
    }
    if (t > 0) {
#pragma unroll
      for (int j = 0; j < 8; ++j) {
        const int idx = j * 256 + tid;
        const int r = idx >> 7, c4 = idx & 127;
        const int cc8 = c4 >> 1, hf = c4 & 1;
        *(u64*)&h_lds[r * 512 + ((cc8 ^ (r & 7)) << 3) + (hf << 2)] = v8[j];
      }
    }
    __syncthreads();   // the ONLY barrier per step
    // 4. h-MFMA
    floatx4 acc = (floatx4){0.f, 0.f, 0.f, 0.f};
    if (t > 0) {
      floatx4 acc1 = (floatx4){0.f, 0.f, 0.f, 0.f};
#pragma unroll
      for (int ks = 0; ks < 16; ks += 2) {
        const int slot0 = (ks * 4 + q) ^ (l15 & 7);
        bf16x8 a0 = *(const bf16x8*)&h_lds[l15 * 512 + slot0 * 8];
        acc = mfma16(a0, bh[ks], acc);
        const int slot1 = ((ks + 1) * 4 + q) ^ (l15 & 7);
        bf16x8 a1 = *(const bf16x8*)&h_lds[l15 * 512 + slot1 * 8];
        acc1 = mfma16(a1, bh[ks + 1], acc1);
      }
      acc += acc1;
    }
    // 5. x-MFMA for gin(t+1) — before the h store (single-buffer ordering)
    floatx4 gx0 = (floatx4){bias_r, bias_r, bias_r, bias_r};
    floatx4 gx1 = (floatx4){0.f, 0.f, 0.f, 0.f};
    if (t < 127) {
#pragma unroll
      for (int ks = 0; ks < 32; ks += 2) {
        const int c0 = ks * 4 + q;
        const int slot0 = (c0 & ~7) | ((c0 & 7) ^ (l15 & 7));
        bf16x8 a0 = *(const bf16x8*)&x_lds[l15 * 1024 + slot0 * 8];
        gx0 = mfma16(a0, bx[ks], gx0);
        const int c1 = (ks + 1) * 4 + q;
        const int slot1 = (c1 & ~7) | ((c1 & 7) ^ (l15 & 7));
        bf16x8 a1 = *(const bf16x8*)&x_lds[l15 * 1024 + slot1 * 8];
        gx1 = mfma16(a1, bx[ks + 1], gx1);
      }
    }
    // 6. g = acc + gin(t) -> wave-local transpose -> activations -> h store
#pragma unroll
    for (int rg = 0; rg < 4; ++rg)
      gsc[wv][q * 4 + rg][l15] = acc[rg] + gin[rg];
    const float gi = gsc[wv][l15][q];
    const float gf = gsc[wv][l15][4 + q];
    const float gg = gsc[wv][l15][8 + q];
    const float go = gsc[wv][l15][12 + q];
    const float iv = sigf(gi), fv = sigf(gf), gv = tanh_(gg), ov = sigf(go);
    c = fv * c + iv * gv;
    const float h = ov * tanh_(c);
    const u32 hv = (u32)f2bf(h);
    const u32 p1 = (u32)__shfl_xor((int)hv, 16);
    const u32 lo32 = hv | (p1 << 16);
    const u64 w64 = (u64)lo32 | ((u64)(u32)__shfl_xor((int)lo32, 32) << 32);
    if (q == 0)
      __hip_atomic_store(
          (u64*)&out[((long)s * 32 + b_glob) * 1024 + dir * 512 + u0 + wv * 4],
          w64, __ATOMIC_RELAXED, __HIP_MEMORY_SCOPE_AGENT);
    gin = gx0 + gx1;
  }
}

// ---------------------------------------------------------------------------
// CRF: one block per (task, batch). Double-buffered alpha: 1 barrier/step.
// ---------------------------------------------------------------------------
template <int K>
static __device__ void crf_body(const float* __restrict__ feat, int off,
                                const int* __restrict__ labels, int b,
                                const float* __restrict__ start,
                                const float* __restrict__ end_,
                                const float* __restrict__ trans,
                                float* __restrict__ outp,
                                float* transT, float (*alpha)[64],
                                float* red)
{
  const int tid = threadIdx.x;
  for (int i = tid; i < K * K; i += 256) {
    int kk = i / K, kp2 = i % K;
    transT[kp2 * 65 + kk] = trans[i];
  }
  if (tid < K) alpha[0][tid] = start[tid] + feat[b * 96 + off + tid];
  __syncthreads();
  constexpr int Kq = K / 4;
  const int kp = tid >> 2, k4 = tid & 3;
  const bool act = kp < K;
  int p = 0;
  for (int s = 1; s < 128; ++s) {
    float x[Kq];
    float mx = -3e38f;
    if (act) {
      const float* tr = &transT[kp * 65 + k4 * Kq];
      const float* al = &alpha[p][k4 * Kq];
#pragma unroll
      for (int i2 = 0; i2 < Kq; ++i2) { x[i2] = al[i2] + tr[i2]; mx = fmaxf(mx, x[i2]); }
    }
    mx = fmaxf(mx, __shfl_xor(mx, 1));
    mx = fmaxf(mx, __shfl_xor(mx, 2));
    float ss = 0.f;
    if (act) {
#pragma unroll
      for (int i2 = 0; i2 < Kq; ++i2) ss += __expf(x[i2] - mx);
    }
    ss += __shfl_xor(ss, 1);
    ss += __shfl_xor(ss, 2);
    if (act && k4 == 0)
      alpha[p ^ 1][kp] = mx + __logf(ss) + feat[(s * 32 + b) * 96 + off + kp];
    __syncthreads();
    p ^= 1;
  }
  if (tid < 128) {
    const int tg = labels[tid * 32 + b];
    float term = feat[(tid * 32 + b) * 96 + off + tg];
    if (tid == 0) term += start[tg];
    else          term += trans[labels[(tid - 1) * 32 + b] * K + tg];
    if (tid == 127) term += end_[tg];
    red[tid] = term;
  }
  __syncthreads();
  if (tid == 0) {
    float num = 0.f;
    for (int i = 0; i < 128; ++i) num += red[i];
    float mx = -3e38f;
    for (int k = 0; k < K; ++k) mx = fmaxf(mx, alpha[p][k] + end_[k]);
    float ss = 0.f;
    for (int k = 0; k < K; ++k) ss += __expf(alpha[p][k] + end_[k] - mx);
    const float den = mx + __logf(ss);
    atomicAdd(outp, den - num);
  }
}

__global__ __launch_bounds__(256) void crf_kernel(
    const float* __restrict__ feat,
    const int* __restrict__ labp, const int* __restrict__ labm,
    const float* __restrict__ stp, const float* __restrict__ enp, const float* __restrict__ trp,
    const float* __restrict__ stm, const float* __restrict__ enm, const float* __restrict__ trm,
    float* __restrict__ outp)
{
  __shared__ float transT[64 * 65];
  __shared__ float alpha[2][64];
  __shared__ float red[128];
  const int task = blockIdx.x >> 5, b = blockIdx.x & 31;
  if (task == 0) crf_body<32>(feat, 0,  labp, b, stp, enp, trp, outp, transT, alpha, red);
  else           crf_body<64>(feat, 32, labm, b, stm, enm, trm, outp, transT, alpha, red);
}

// ---------------------------------------------------------------------------
// launch
// ---------------------------------------------------------------------------
extern "C" void kernel_launch(void* const* d_in, const int* in_sizes, int n_in,
                              void* d_out, int out_size, void* d_ws, size_t ws_size,
                              hipStream_t stream) {
  const float* src  = (const float*)d_in[0];
  const float* bert = (const float*)d_in[1];
  const int*   labp = (const int*)d_in[2];
  const int*   labm = (const int*)d_in[3];
  const float* w_ih = (const float*)d_in[4];
  const float* w_hh = (const float*)d_in[5];
  const float* b_ih = (const float*)d_in[6];
  const float* b_hh = (const float*)d_in[7];
  const float* hwp  = (const float*)d_in[8];
  const float* hbp  = (const float*)d_in[9];
  const float* hwm  = (const float*)d_in[10];
  const float* hbm  = (const float*)d_in[11];
  const float* stp  = (const float*)d_in[12];
  const float* enp  = (const float*)d_in[13];
  const float* trp  = (const float*)d_in[14];
  const float* stm  = (const float*)d_in[15];
  const float* enm  = (const float*)d_in[16];
  const float* trm  = (const float*)d_in[17];

  char* ws = (char*)d_ws;
  u16*   Wih    = (u16*)(ws + 0);          // [2][2][2048][1024] bf16 16.8 MB
  u16*   Whh    = (u16*)(ws + 16777216);   // [2][2][2048][512] bf16 8.4 MB
  u16*   emb    = (u16*)(ws + 25165824);   // [128][32][1024] bf16 8.4 MB
  u16*   Wheads = (u16*)(ws + 33554432);   // 96x1024 bf16
  float* bsum   = (float*)(ws + 33751040); // [2][2][2048]
  float* hb     = (float*)(ws + 33783808); // [96]
  float* feat   = (float*)(ws + 33784320); // [4096][96] fp32
  u16*   out0   = (u16*)(ws + 35357184);   // [128][32][1024] bf16
  u16*   out1   = (u16*)(ws + 43745792);   // [128][32][1024] bf16
  float* dout   = (float*)d_out;

  // sentinel fill: bf16 0xFFFF = NaN, unreachable for valid h in (-1,1)
  hipMemsetAsync(out0, 0xFF, 8388608, stream);
  hipMemsetAsync(out1, 0xFF, 8388608, stream);

  hipLaunchKernelGGL(prep_kernel, dim3(2048), dim3(256), 0, stream,
      w_ih, w_hh, b_ih, b_hh, src, bert, hwp, hwm, hbp, hbm,
      Wih, Whh, emb, Wheads, bsum, hb, dout);

  // layer 0: x = emb
  hipLaunchKernelGGL(lstm_rec, dim3(128), dim3(256), 0, stream,
      emb, out0, Wih, Whh, bsum);

  // layer 1: x = out0
  hipLaunchKernelGGL(lstm_rec, dim3(128), dim3(256), 0, stream,
      out0, out1, Wih + 4194304, Whh + 2097152, bsum + 4096);

  // heads: out1@[96,1024]^T + hb -> feat[4096][96]
  hipLaunchKernelGGL(gemm_nt, dim3(1, 32), dim3(256), 0, stream,
      out1, 1024, Wheads, 1024, feat, 96, 4096, 96, 1024, hb);

  hipLaunchKernelGGL(crf_kernel, dim3(64), dim3(256), 0, stream,
      feat, labp, labm, stp, enp, trp, stm, enm, trm, dout);
}